// Round 3
// baseline (226.655 us; speedup 1.0000x reference)
//
#include <hip/hip_runtime.h>
#include <hip/hip_bf16.h>

// 3x3 conv pad=1 stride=1, NHWC fp32 -> bf16 MFMA implicit GEMM.
//   M = 32*56*56 = 100352, N = 256, K = 9*128 = 1152
// R3: XOR-swizzled LDS (kills 4-8 way ds_read_b128 bank conflicts seen in R2:
// SQ_LDS_BANK_CONFLICT 7.2e6) + BK=64 (half the barrier drains, 32 MFMA per
// vmcnt(0)). Compute in two 32-k phases to cap VGPR.

#define NIMG 32
#define HH 56
#define WW 56
#define PH 58
#define PW 58
#define CIN 128
#define COUT 256
#define KTOT 1152
#define PAD_ELEMS (NIMG * PH * PW * CIN)

#define BK 64               // k per LDS tile (2 x 32-k MFMA phases)
#define NITER (KTOT / BK)   // 18

typedef __attribute__((ext_vector_type(8))) short bf16x8;
typedef __attribute__((ext_vector_type(4))) short s16x4;
typedef __attribute__((ext_vector_type(4))) float f32x4;

__device__ __forceinline__ short f2bf(float x) {
    union { __hip_bfloat16 b; short s; } u;
    u.b = __float2bfloat16(x);
    return u.s;
}

typedef const void __attribute__((address_space(1)))* gas1_t;
typedef void __attribute__((address_space(3)))* las3_t;
__device__ __forceinline__ void async16(short* lds, const short* g) {
    __builtin_amdgcn_global_load_lds((gas1_t)g, (las3_t)lds, 16, 0, 0);
}

// ---- pack 1: fp32 NHWC -> padded bf16 (32,58,58,128), zero halo -------------
__global__ __launch_bounds__(256) void pack_input(const float* __restrict__ in,
                                                  short* __restrict__ pad) {
    const int tid  = blockIdx.x * 256 + threadIdx.x;
    const int flat = tid * 8;
    const int c8   = flat & (CIN - 1);
    const int rest = flat >> 7;
    const int iw   = rest % PW;
    const int r2   = rest / PW;
    const int ih   = r2 % PH;
    const int img  = r2 / PH;
    bf16x8 v = (bf16x8)0;
    if (ih >= 1 && ih <= HH && iw >= 1 && iw <= WW) {
        const float* p = in + (((size_t)(img * HH + ih - 1) * WW + (iw - 1)) * CIN + c8);
        const float4 x0 = *(const float4*)p;
        const float4 x1 = *(const float4*)(p + 4);
        v.s0 = f2bf(x0.x); v.s1 = f2bf(x0.y); v.s2 = f2bf(x0.z); v.s3 = f2bf(x0.w);
        v.s4 = f2bf(x1.x); v.s5 = f2bf(x1.y); v.s6 = f2bf(x1.z); v.s7 = f2bf(x1.w);
    }
    *(bf16x8*)(pad + flat) = v;
}

// ---- pack 2: weights (K=1152, N=256) fp32 -> bf16 transposed [n][k] ---------
__global__ __launch_bounds__(256) void pack_wgt(const float* __restrict__ w,
                                                short* __restrict__ wt) {
    __shared__ short tile[32][33];
    const int k0 = blockIdx.x * 32;
    const int n0 = blockIdx.y * 32;
    const int t  = threadIdx.x;
    {
        const int kl  = t >> 3;
        const int nl4 = (t & 7) * 4;
        const float4 x = *(const float4*)(w + (size_t)(k0 + kl) * COUT + n0 + nl4);
        tile[kl][nl4 + 0] = f2bf(x.x);
        tile[kl][nl4 + 1] = f2bf(x.y);
        tile[kl][nl4 + 2] = f2bf(x.z);
        tile[kl][nl4 + 3] = f2bf(x.w);
    }
    __syncthreads();
    {
        const int nl  = t >> 3;
        const int kl4 = (t & 7) * 4;
        s16x4 v;
        v.x = tile[kl4 + 0][nl];
        v.y = tile[kl4 + 1][nl];
        v.z = tile[kl4 + 2][nl];
        v.w = tile[kl4 + 3][nl];
        *(s16x4*)(wt + (size_t)(n0 + nl) * KTOT + k0 + kl4) = v;
    }
}

// ---- GEMM: 128x128 tile, BK=64, XOR-swizzled LDS, 16x16x32 bf16 MFMA -------
// LDS: row r (128B = 8 chunks of 16B); phys chunk p holds logical k-chunk
// p ^ (r&7). Staging chunk c = 256j + t -> (r = 32j + (t>>3), p = t&7), so the
// global source k-chunk is (t&7) ^ ((t>>3)&7)  (constant across j).
__global__ __launch_bounds__(256) void conv_mfma(const short* __restrict__ apad,
                                                 const short* __restrict__ bwt,
                                                 const float* __restrict__ bias,
                                                 float* __restrict__ out) {
    __shared__ short As[128 * BK];  // 16 KB
    __shared__ short Bs[128 * BK];  // 16 KB

    const int t  = threadIdx.x;
    const int l  = t & 63;
    const int w  = t >> 6;
    const int m0 = blockIdx.y * 128;
    const int n0 = blockIdx.x * 128;

    // staging source addresses (4 rows per thread, one 16B chunk each)
    const int kc = (t & 7) ^ ((t >> 3) & 7);  // swizzled logical k-chunk
    int abase[4], bbase[4];
#pragma unroll
    for (int j = 0; j < 4; ++j) {
        const int r   = (t >> 3) + 32 * j;
        const int m   = m0 + r;
        const int img = m / (HH * WW);
        const int rem = m - img * (HH * WW);
        const int oh  = rem / WW;
        const int ow  = rem - oh * WW;
        abase[j] = ((img * PH + oh) * PW + ow) * CIN + kc * 8;
        bbase[j] = (n0 + r) * KTOT + kc * 8;
    }

    f32x4 acc[4][4];
#pragma unroll
    for (int i = 0; i < 4; ++i)
#pragma unroll
        for (int j = 0; j < 4; ++j) { f32x4 z = {0.f, 0.f, 0.f, 0.f}; acc[i][j] = z; }

    const int wm = w & 1;
    const int wn = w >> 1;
    const int fr = l & 15;
    const int fq = l >> 4;
    const int sw = fr & 7;   // row-swizzle key for fragment reads

    for (int kt = 0; kt < NITER; ++kt) {
        const int fhw  = kt >> 1;             // 2 x 64-k tiles per (fh,fw) plane
        const int ci0  = (kt & 1) * 64;
        const int fh   = fhw / 3;
        const int fw   = fhw - fh * 3;
        const int aoff = (fh * PW + fw) * CIN + ci0;
        const int boff = kt * BK;

        __syncthreads();
#pragma unroll
        for (int j = 0; j < 4; ++j) {
            async16(As + (j * 256 + w * 64) * 8, apad + abase[j] + aoff);
            async16(Bs + (j * 256 + w * 64) * 8, bwt + bbase[j] + boff);
        }
        __syncthreads();  // compiler inserts vmcnt(0) drain here

#pragma unroll
        for (int kk = 0; kk < 2; ++kk) {
            const int q = (kk * 4 + fq);
            bf16x8 af[4], bf[4];
#pragma unroll
            for (int i = 0; i < 4; ++i)
                af[i] = *(bf16x8*)&As[(wm * 64 + i * 16 + fr) * BK + (q ^ sw) * 8];
#pragma unroll
            for (int j = 0; j < 4; ++j)
                bf[j] = *(bf16x8*)&Bs[(wn * 64 + j * 16 + fr) * BK + (q ^ sw) * 8];
#pragma unroll
            for (int i = 0; i < 4; ++i)
#pragma unroll
                for (int j = 0; j < 4; ++j)
                    acc[i][j] = __builtin_amdgcn_mfma_f32_16x16x32_bf16(af[i], bf[j], acc[i][j], 0, 0, 0);
        }
    }

    // ---- epilogue: bias + ReLU. D: col(N)=lane&15, row(M)=quad*4+reg (m89)
#pragma unroll
    for (int j = 0; j < 4; ++j) {
        const int n  = n0 + wn * 64 + j * 16 + fr;
        const float bj = bias[n];
#pragma unroll
        for (int i = 0; i < 4; ++i) {
            const int mrow = m0 + wm * 64 + i * 16 + fq * 4;
#pragma unroll
            for (int r = 0; r < 4; ++r) {
                const float v = acc[i][j][r] + bj;
                out[(size_t)(mrow + r) * COUT + n] = v > 0.f ? v : 0.f;
            }
        }
    }
}

extern "C" void kernel_launch(void* const* d_in, const int* in_sizes, int n_in,
                              void* d_out, int out_size, void* d_ws, size_t ws_size,
                              hipStream_t stream) {
    const float* in   = (const float*)d_in[0];
    const float* wgt  = (const float*)d_in[1];
    const float* bias = (const float*)d_in[2];
    float* out = (float*)d_out;

    short* pad = (short*)d_ws;
    short* wt  = (short*)d_ws + PAD_ELEMS;

    pack_input<<<PAD_ELEMS / 8 / 256, 256, 0, stream>>>(in, pad);
    pack_wgt<<<dim3(KTOT / 32, COUT / 32), 256, 0, stream>>>(wgt, wt);

    dim3 grid(COUT / 128, (NIMG * HH * WW) / 128);   // (2, 784)
    conv_mfma<<<grid, 256, 0, stream>>>(pad, wt, bias, out);
}

// Round 4
// 221.721 us; speedup vs baseline: 1.0223x; 1.0223x over previous
//
#include <hip/hip_runtime.h>
#include <hip/hip_bf16.h>

// 3x3 conv pad=1 stride=1, NHWC fp32 -> bf16 MFMA implicit GEMM.
//   M = 32*56*56 = 100352, N = 256, K = 9*128 = 1152
// R4: double-buffered LDS (distinct __shared__ arrays so alias analysis can't
// serialize), global_load_lds for tile k+1 issued BEFORE compute of tile k ->
// the vmcnt(0) drain at the next barrier lands a full compute-phase after
// issue (R2/R3 exposed the full memory latency every iter: MfmaUtil 23%).
// BK=32, superrow(128B)-XOR swizzled LDS keeps ds_read_b128 conflict-free.

#define NIMG 32
#define HH 56
#define WW 56
#define PH 58
#define PW 58
#define CIN 128
#define COUT 256
#define KTOT 1152
#define PAD_ELEMS (NIMG * PH * PW * CIN)

#define BK 32
#define KITERS (KTOT / BK)   // 36

typedef __attribute__((ext_vector_type(8))) short bf16x8;
typedef __attribute__((ext_vector_type(4))) short s16x4;
typedef __attribute__((ext_vector_type(4))) float f32x4;

__device__ __forceinline__ short f2bf(float x) {
    union { __hip_bfloat16 b; short s; } u;
    u.b = __float2bfloat16(x);
    return u.s;
}

typedef const void __attribute__((address_space(1)))* gas1_t;
typedef void __attribute__((address_space(3)))* las3_t;
__device__ __forceinline__ void async16(short* lds, const short* g) {
    __builtin_amdgcn_global_load_lds((gas1_t)g, (las3_t)lds, 16, 0, 0);
}

// ---- pack 1: fp32 NHWC -> padded bf16 (32,58,58,128), zero halo -------------
__global__ __launch_bounds__(256) void pack_input(const float* __restrict__ in,
                                                  short* __restrict__ pad) {
    const int tid  = blockIdx.x * 256 + threadIdx.x;
    const int flat = tid * 8;
    const int c8   = flat & (CIN - 1);
    const int rest = flat >> 7;
    const int iw   = rest % PW;
    const int r2   = rest / PW;
    const int ih   = r2 % PH;
    const int img  = r2 / PH;
    bf16x8 v = (bf16x8)0;
    if (ih >= 1 && ih <= HH && iw >= 1 && iw <= WW) {
        const float* p = in + (((size_t)(img * HH + ih - 1) * WW + (iw - 1)) * CIN + c8);
        const float4 x0 = *(const float4*)p;
        const float4 x1 = *(const float4*)(p + 4);
        v.s0 = f2bf(x0.x); v.s1 = f2bf(x0.y); v.s2 = f2bf(x0.z); v.s3 = f2bf(x0.w);
        v.s4 = f2bf(x1.x); v.s5 = f2bf(x1.y); v.s6 = f2bf(x1.z); v.s7 = f2bf(x1.w);
    }
    *(bf16x8*)(pad + flat) = v;
}

// ---- pack 2: weights (K=1152, N=256) fp32 -> bf16 transposed [n][k] ---------
__global__ __launch_bounds__(256) void pack_wgt(const float* __restrict__ w,
                                                short* __restrict__ wt) {
    __shared__ short tile[32][33];
    const int k0 = blockIdx.x * 32;
    const int n0 = blockIdx.y * 32;
    const int t  = threadIdx.x;
    {
        const int kl  = t >> 3;
        const int nl4 = (t & 7) * 4;
        const float4 x = *(const float4*)(w + (size_t)(k0 + kl) * COUT + n0 + nl4);
        tile[kl][nl4 + 0] = f2bf(x.x);
        tile[kl][nl4 + 1] = f2bf(x.y);
        tile[kl][nl4 + 2] = f2bf(x.z);
        tile[kl][nl4 + 3] = f2bf(x.w);
    }
    __syncthreads();
    {
        const int nl  = t >> 3;
        const int kl4 = (t & 7) * 4;
        s16x4 v;
        v.x = tile[kl4 + 0][nl];
        v.y = tile[kl4 + 1][nl];
        v.z = tile[kl4 + 2][nl];
        v.w = tile[kl4 + 3][nl];
        *(s16x4*)(wt + (size_t)(n0 + nl) * KTOT + k0 + kl4) = v;
    }
}

// ---- GEMM: 128x128 tile, BK=32, dbuf LDS, 16x16x32 bf16 MFMA ---------------
// LDS tile = 128 rows x 32 k (64 B rows). Swizzle unit = superrow (2 rows,
// 128 B = 8 chunks of 16 B): phys chunk p holds logical chunk p ^ (s&7),
// logical chunk L = (row&1)*4 + kchunk. Fragment read bank group =
// 4*(((R&1)*4+fq) ^ ((R>>1)&7)) -> 2 lanes/bank-group = conflict-free.
__global__ __launch_bounds__(256) void conv_mfma(const short* __restrict__ apad,
                                                 const short* __restrict__ bwt,
                                                 const float* __restrict__ bias,
                                                 float* __restrict__ out) {
    __shared__ short As0[128 * BK], As1[128 * BK];   // 8 KB each
    __shared__ short Bs0[128 * BK], Bs1[128 * BK];   // total 32 KB

    const int t  = threadIdx.x;
    const int l  = t & 63;
    const int w  = t >> 6;
    const int m0 = blockIdx.y * 128;
    const int n0 = blockIdx.x * 128;

    // staging: thread t -> phys chunk (t&7) in superrow (t>>3) (+32 for j=1)
    // logical L = (t&7) ^ ((t>>3)&7) -> row = 2*(t>>3) + (L>>2) (+64), kc = L&3
    const int Lc = (t & 7) ^ ((t >> 3) & 7);
    const int kc = Lc & 3;
    int abase[2], bbase[2];
#pragma unroll
    for (int j = 0; j < 2; ++j) {
        const int r   = 2 * (t >> 3) + (Lc >> 2) + j * 64;
        const int m   = m0 + r;
        const int img = m / (HH * WW);
        const int rem = m - img * (HH * WW);
        const int oh  = rem / WW;
        const int ow  = rem - oh * WW;
        abase[j] = ((img * PH + oh) * PW + ow) * CIN + kc * 8;
        bbase[j] = (n0 + r) * KTOT + kc * 8;
    }

    f32x4 acc[4][4];
#pragma unroll
    for (int i = 0; i < 4; ++i)
#pragma unroll
        for (int j = 0; j < 4; ++j) { f32x4 z = {0.f, 0.f, 0.f, 0.f}; acc[i][j] = z; }

    const int wm = w & 1;
    const int wn = w >> 1;
    const int fr = l & 15;
    const int fq = l >> 4;

#define STAGE(KT, AS, BS) do {                                              \
        const int _fhw  = (KT) >> 2;                                        \
        const int _fh   = _fhw / 3;                                         \
        const int _fw   = _fhw - _fh * 3;                                   \
        const int _aoff = (_fh * PW + _fw) * CIN + ((KT) & 3) * 32;         \
        const int _boff = (KT) * BK;                                        \
        _Pragma("unroll")                                                   \
        for (int _j = 0; _j < 2; ++_j) {                                    \
            async16((AS) + (_j * 256 + w * 64) * 8, apad + abase[_j] + _aoff); \
            async16((BS) + (_j * 256 + w * 64) * 8, bwt + bbase[_j] + _boff); \
        }                                                                   \
    } while (0)

    // swizzled fragment address (elements): row R, k-chunk fq
#define FRAG(BASE, R) \
    (*(const bf16x8*)((BASE) + (((R) >> 1) << 6) + \
     (((((R) & 1) << 2) | fq) ^ (((R) >> 1) & 7)) * 8))

#define COMPUTE(AS, BS) do {                                                \
        bf16x8 _af[4], _bf[4];                                              \
        _Pragma("unroll")                                                   \
        for (int _i = 0; _i < 4; ++_i) _af[_i] = FRAG(AS, wm * 64 + _i * 16 + fr); \
        _Pragma("unroll")                                                   \
        for (int _j = 0; _j < 4; ++_j) _bf[_j] = FRAG(BS, wn * 64 + _j * 16 + fr); \
        _Pragma("unroll")                                                   \
        for (int _i = 0; _i < 4; ++_i)                                      \
            _Pragma("unroll")                                               \
            for (int _j = 0; _j < 4; ++_j)                                  \
                acc[_i][_j] = __builtin_amdgcn_mfma_f32_16x16x32_bf16(      \
                    _af[_i], _bf[_j], acc[_i][_j], 0, 0, 0);                \
    } while (0)

    STAGE(0, As0, Bs0);
    for (int kt = 0; kt < KITERS; kt += 2) {
        __syncthreads();                       // buf0 staged; buf1 readers done
        STAGE(kt + 1, As1, Bs1);               // in flight during compute
        COMPUTE(As0, Bs0);
        __syncthreads();                       // buf1 staged; buf0 readers done
        if (kt + 2 < KITERS) STAGE(kt + 2, As0, Bs0);
        COMPUTE(As1, Bs1);
    }

    // ---- epilogue: bias + ReLU. D: col(N)=lane&15, row(M)=quad*4+reg (m89)
#pragma unroll
    for (int j = 0; j < 4; ++j) {
        const int n  = n0 + wn * 64 + j * 16 + fr;
        const float bj = bias[n];
#pragma unroll
        for (int i = 0; i < 4; ++i) {
            const int mrow = m0 + wm * 64 + i * 16 + fq * 4;
#pragma unroll
            for (int r = 0; r < 4; ++r) {
                const float v = acc[i][j][r] + bj;
                out[(size_t)(mrow + r) * COUT + n] = v > 0.f ? v : 0.f;
            }
        }
    }
#undef STAGE
#undef FRAG
#undef COMPUTE
}

extern "C" void kernel_launch(void* const* d_in, const int* in_sizes, int n_in,
                              void* d_out, int out_size, void* d_ws, size_t ws_size,
                              hipStream_t stream) {
    const float* in   = (const float*)d_in[0];
    const float* wgt  = (const float*)d_in[1];
    const float* bias = (const float*)d_in[2];
    float* out = (float*)d_out;

    short* pad = (short*)d_ws;
    short* wt  = (short*)d_ws + PAD_ELEMS;

    pack_input<<<PAD_ELEMS / 8 / 256, 256, 0, stream>>>(in, pad);
    pack_wgt<<<dim3(KTOT / 32, COUT / 32), 256, 0, stream>>>(wgt, wt);

    dim3 grid(COUT / 128, (NIMG * HH * WW) / 128);   // (2, 784)
    conv_mfma<<<grid, 256, 0, stream>>>(pad, wt, bias, out);
}